// Round 4
// baseline (263.469 us; speedup 1.0000x reference)
//
#include <hip/hip_runtime.h>
#include <math.h>

typedef __attribute__((ext_vector_type(8))) short short8;
typedef __attribute__((ext_vector_type(4))) float float4v;
typedef unsigned int uint;

#define BATCH 8
#define SEQ   4096
#define DIM   768
#define HID   512
#define M_TOK (BATCH * SEQ)   // 32768

// ---------- helpers ----------
static __device__ __forceinline__ short f2bf_rne(float x) {
    unsigned int u = __float_as_uint(x);
    unsigned int r = (u + 0x7FFFu + ((u >> 16) & 1u)) >> 16;   // RNE
    return (short)r;
}
// pack two floats -> 2 bf16 (truncate) in ONE v_perm_b32. lo=bf16(a), hi=bf16(b).
static __device__ __forceinline__ uint pack_bf2(float a, float b) {
    return __builtin_amdgcn_perm(__float_as_uint(b), __float_as_uint(a), 0x07060302u);
}
union FragU { uint u[4]; short8 s; };

// ---------- prep: transpose W1 -> W1T (bf16, [HID][DIM]) ----------
__global__ __launch_bounds__(256) void prep_kernel(const float* __restrict__ W1,
                                                   short* __restrict__ W1T) {
    int idx = blockIdx.x * 256 + threadIdx.x;        // 0 .. DIM*HID-1
    if (idx < DIM * HID) {
        int k = idx / HID, n = idx % HID;            // W1 row-major [DIM][HID]
        W1T[n * DIM + k] = f2bf_rne(W1[idx]);
    }
}

// ---------- MLP: full N=512 per block. A staged once via dbuf LDS panels; B direct
// global->frag (L2-resident 786 KB). partial[w][row] = 128-col slice of relu(A.W1+b1)*W2.
// Tile: 64(M) x 512(N in-block, 128 per wave), BK=64 -> 12 panels, 2 k-steps each.
__global__ __launch_bounds__(256) void mlp_kernel(const float* __restrict__ A,
                                                  const short* __restrict__ BT,
                                                  const float* __restrict__ b1,
                                                  const float* __restrict__ W2,
                                                  float* __restrict__ partial) {
    __shared__ short As[2][64 * 72];   // 64 rows x 64k +8 pad, bf16: 18.4 KB total

    const int m0 = blockIdx.x * 64;
    const int tid = threadIdx.x;
    const int wave = tid >> 6, lane = tid & 63;
    const int quad = lane >> 4, r = lane & 15;
    const int srow = tid >> 2, scol = (tid & 3) * 16;   // stage: 16 floats per thread/panel
    const float* aPtr = A + (size_t)(m0 + srow) * DIM + scol;
    const int lw = srow * 72 + scol;
    const short* bPtr = BT + (size_t)(wave * 128 + r) * DIM + quad * 8;

    float4v s[4];
    short8  bfr[2][8];
#pragma unroll
    for (int i = 0; i < 4; i++) s[i] = *(const float4v*)(aPtr + i * 4);
#pragma unroll
    for (int j = 0; j < 8; j++) bfr[0][j] = *(const short8*)(bPtr + j * 16 * DIM);
    {   // stage panel 0
        uint pk[8];
#pragma unroll
        for (int i = 0; i < 4; i++) {
            pk[2 * i]     = pack_bf2(s[i][0], s[i][1]);
            pk[2 * i + 1] = pack_bf2(s[i][2], s[i][3]);
        }
        *(short8*)(&As[0][lw])     = *(short8*)&pk[0];
        *(short8*)(&As[0][lw + 8]) = *(short8*)&pk[4];
    }
    float4v acc[4][8] = {};
    __syncthreads();

    int ks = 0;
#pragma unroll
    for (int p = 0; p < 12; ++p) {
        const int cur = p & 1;
        if (p < 11) {                       // prefetch next A panel into regs
            const float* ap = aPtr + (p + 1) * 64;
#pragma unroll
            for (int i = 0; i < 4; i++) s[i] = *(const float4v*)(ap + i * 4);
        }
#pragma unroll
        for (int h = 0; h < 2; ++h, ++ks) {
            const int bb = ks & 1;
            if (ks < 23) {                  // prefetch next k-step's B frags
                const short* bp = bPtr + (ks + 1) * 32;
#pragma unroll
                for (int j = 0; j < 8; j++)
                    bfr[bb ^ 1][j] = *(const short8*)(bp + j * 16 * DIM);
            }
            FragU af[4];
#pragma unroll
            for (int mf = 0; mf < 4; mf++)
                af[mf].s = *(const short8*)(&As[cur][(mf * 16 + r) * 72 + h * 32 + quad * 8]);
#pragma unroll
            for (int mf = 0; mf < 4; mf++)
#pragma unroll
                for (int j = 0; j < 8; j++)
                    acc[mf][j] = __builtin_amdgcn_mfma_f32_16x16x32_bf16(
                        af[mf].s, bfr[bb][j], acc[mf][j], 0, 0, 0);
        }
        if (p < 11) {                       // stage next panel into the other buffer
            uint pk[8];
#pragma unroll
            for (int i = 0; i < 4; i++) {
                pk[2 * i]     = pack_bf2(s[i][0], s[i][1]);
                pk[2 * i + 1] = pack_bf2(s[i][2], s[i][3]);
            }
            *(short8*)(&As[cur ^ 1][lw])     = *(short8*)&pk[0];
            *(short8*)(&As[cur ^ 1][lw + 8]) = *(short8*)&pk[4];
        }
        __syncthreads();
    }

    // epilogue: h = relu(acc + b1); p(row) = sum over this wave's 128-col slice of h*W2
    float b1v[8], w2v[8];
#pragma unroll
    for (int j = 0; j < 8; j++) {
        int gc = wave * 128 + j * 16 + r;
        b1v[j] = b1[gc];
        w2v[j] = W2[gc];
    }
#pragma unroll
    for (int mf = 0; mf < 4; mf++)
#pragma unroll
        for (int v = 0; v < 4; v++) {
            float pp = 0.f;
#pragma unroll
            for (int j = 0; j < 8; j++) {
                float hh = acc[mf][j][v] + b1v[j];
                hh = hh > 0.f ? hh : 0.f;
                pp += hh * w2v[j];
            }
#pragma unroll
            for (int off = 1; off < 16; off <<= 1) pp += __shfl_xor(pp, off, 64);
            if (r == 0)
                partial[(size_t)wave * M_TOK + m0 + mf * 16 + quad * 4 + v] = pp;
        }
}

// ---------- boundary: sum partials -> logit, hard bits, per-batch scan -> segment starts ----------
__global__ __launch_bounds__(1024) void boundary_kernel(const float* __restrict__ partial,
                                                        const float* __restrict__ b2p,
                                                        const float* __restrict__ noise,
                                                        int* __restrict__ starts,   // [BATCH][SEQ+1]
                                                        int* __restrict__ nseg,     // [BATCH]
                                                        int* __restrict__ nbcount) {// [BATCH]
    const int b = blockIdx.x, tid = threadIdx.x;
    const int base = tid * 4;
    const float b2 = b2p[0];
    int h[4], c = 0;
#pragma unroll
    for (int j = 0; j < 4; j++) {
        int l = base + j;
        float u = noise[b * SEQ + l];
        float nz = logf(u) - log1pf(-u);
        float lg = b2 + nz;
#pragma unroll
        for (int q = 0; q < 4; q++) lg += partial[(size_t)q * M_TOK + b * SEQ + l];
        h[j] = (lg > 0.f) ? 1 : 0;
        c += h[j];
    }
    const int lane = tid & 63, wid = tid >> 6;
    int inc = c;
    for (int off = 1; off < 64; off <<= 1) {
        int t = __shfl_up(inc, off, 64);
        if (lane >= off) inc += t;
    }
    __shared__ int wtot[16], woff[16], extra[2];
    if (lane == 63) wtot[wid] = inc;
    if (tid == 1023) extra[0] = h[3];
    __syncthreads();
    if (tid == 0) {
        int s = 0;
        for (int i = 0; i < 16; i++) { woff[i] = s; s += wtot[i]; }
        extra[1] = s;
    }
    __syncthreads();
    int run = (inc - c) + woff[wid];       // exclusive prefix of hard bits
#pragma unroll
    for (int j = 0; j < 4; j++) {
        int l = base + j;
        if (h[j]) {
            run++;                          // inclusive count at l == id of next segment
            if (l < SEQ - 1) starts[b * (SEQ + 1) + run] = l + 1;
        }
    }
    if (tid == 0) {
        int total = extra[1];
        int ns = total + (extra[0] ? 0 : 1);
        starts[b * (SEQ + 1)] = 0;
        starts[b * (SEQ + 1) + ns] = SEQ;
        nseg[b] = ns;
        nbcount[b] = total;
    }
}

// ---------- pool: 4 waves/block, one wave per segment slot; zero-fill unused slots ----------
__global__ __launch_bounds__(256) void pool_kernel(const float* __restrict__ hidden,
                                                   const int* __restrict__ starts,
                                                   const int* __restrict__ nseg,
                                                   float* __restrict__ out) {
    const int wid = threadIdx.x >> 6, lane = threadIdx.x & 63;
    const int s = blockIdx.x * 4 + wid, b = blockIdx.y;
    float* orow = out + (size_t)(b * SEQ + s) * DIM;
    const int ns = nseg[b];
    if (s >= ns) {
        float4v z = {0.f, 0.f, 0.f, 0.f};
        *(float4v*)(orow + lane * 4)         = z;
        *(float4v*)(orow + (lane + 64) * 4)  = z;
        *(float4v*)(orow + (lane + 128) * 4) = z;
        return;
    }
    const int st = starts[b * (SEQ + 1) + s];
    const int en = starts[b * (SEQ + 1) + s + 1];
    float4v a0 = {0.f, 0.f, 0.f, 0.f}, a1 = a0, a2 = a0;
    const float* hbase = hidden + (size_t)(b * SEQ) * DIM;
    for (int row = st; row < en; row++) {
        const float* hr = hbase + (size_t)row * DIM;
        a0 += *(const float4v*)(hr + lane * 4);
        a1 += *(const float4v*)(hr + (lane + 64) * 4);
        a2 += *(const float4v*)(hr + (lane + 128) * 4);
    }
    const float invc = 1.f / (float)(en - st);
    a0 *= invc; a1 *= invc; a2 *= invc;
    *(float4v*)(orow + lane * 4)         = a0;
    *(float4v*)(orow + (lane + 64) * 4)  = a1;
    *(float4v*)(orow + (lane + 128) * 4) = a2;
}

// ---------- finalize: loss / num_boundaries / total_positions ----------
__global__ void finalize_kernel(const int* __restrict__ nbcount, float* __restrict__ tail) {
    int nb = 0;
    for (int i = 0; i < BATCH; i++) nb += nbcount[i];
    float ratio = (float)nb / (float)M_TOK;
    float d = fabsf(ratio - 0.25f) - 0.05f;    // PRIOR + 0.05 = 0.25, margin 0.05
    tail[0] = d > 0.f ? d : 0.f;
    tail[1] = (float)nb;
    tail[2] = (float)M_TOK;
}

// ---------- launch ----------
extern "C" void kernel_launch(void* const* d_in, const int* in_sizes, int n_in,
                              void* d_out, int out_size, void* d_ws, size_t ws_size,
                              hipStream_t stream) {
    const float* hidden = (const float*)d_in[0];
    const float* W1     = (const float*)d_in[1];
    const float* b1     = (const float*)d_in[2];
    const float* W2     = (const float*)d_in[3];
    const float* b2     = (const float*)d_in[4];
    const float* noise  = (const float*)d_in[5];

    char* ws = (char*)d_ws;
    short* W1T     = (short*)(ws);                           // 786432 B
    float* partial = (float*)(ws + 786432);                  // 4*32768*4 = 524288 B
    int*   starts  = (int*)(ws + 1310720);                   // 8*4097*4  = 131104 B
    int*   nseg    = (int*)(ws + 1441824);                   // 8*4
    int*   nbcount = nseg + 8;                               // 8*4
    float* out     = (float*)d_out;

    prep_kernel<<<1536, 256, 0, stream>>>(W1, W1T);
    mlp_kernel<<<512, 256, 0, stream>>>(hidden, W1T, b1, W2, partial);
    boundary_kernel<<<BATCH, 1024, 0, stream>>>(partial, b2, noise, starts, nseg, nbcount);
    pool_kernel<<<dim3(SEQ / 4, BATCH), 256, 0, stream>>>(hidden, starts, nseg, out);
    finalize_kernel<<<1, 1, 0, stream>>>(nbcount, out + (size_t)M_TOK * DIM);
}

// Round 5
// 242.540 us; speedup vs baseline: 1.0863x; 1.0863x over previous
//
#include <hip/hip_runtime.h>
#include <math.h>

typedef __attribute__((ext_vector_type(8))) short short8;
typedef __attribute__((ext_vector_type(4))) float float4v;
typedef unsigned int uint;

#define BATCH 8
#define SEQ   4096
#define DIM   768
#define HID   512
#define M_TOK (BATCH * SEQ)   // 32768

// ---------- helpers ----------
static __device__ __forceinline__ short f2bf_rne(float x) {
    unsigned int u = __float_as_uint(x);
    unsigned int r = (u + 0x7FFFu + ((u >> 16) & 1u)) >> 16;   // RNE
    return (short)r;
}
// pack two floats -> 2 bf16 (truncate) in ONE v_perm_b32. lo=bf16(a), hi=bf16(b).
static __device__ __forceinline__ uint pack_bf2(float a, float b) {
    return __builtin_amdgcn_perm(__float_as_uint(b), __float_as_uint(a), 0x07060302u);
}
union FragU { uint u[4]; short8 s; };
// async global->LDS DMA, 16 B per lane; lds dest = uniform base + lane*16
static __device__ __forceinline__ void gl2lds16(const void* g, void* l) {
    __builtin_amdgcn_global_load_lds(
        (const __attribute__((address_space(1))) unsigned int*)g,
        (__attribute__((address_space(3))) unsigned int*)l, 16, 0, 0);
}

// ---------- prep: LDS-tiled transpose W1 [DIM][HID] fp32 -> W1T [HID][DIM] bf16 ----------
__global__ __launch_bounds__(256) void prep_kernel(const float* __restrict__ W1,
                                                   short* __restrict__ W1T) {
    __shared__ float t[64][65];
    const int bk = blockIdx.x % 12, bn = blockIdx.x / 12;   // 12 k-tiles x 8 n-tiles
    const int k0 = bk * 64, n0 = bn * 64;
    const int tr = threadIdx.x >> 6, tc = threadIdx.x & 63;
#pragma unroll
    for (int i = 0; i < 16; i++) {
        int k = tr + i * 4;
        t[k][tc] = W1[(size_t)(k0 + k) * HID + n0 + tc];
    }
    __syncthreads();
#pragma unroll
    for (int i = 0; i < 16; i++) {
        int n = tr + i * 4;
        W1T[(size_t)(n0 + n) * DIM + k0 + tc] = f2bf_rne(t[tc][n]);
    }
}

// ---------- MLP: block = 64M x 512N (full N). A panel DMA'd as fp32 (swizzled),
// B panel DMA'd as bf16. Single-buffer m97 2-barrier K-loop, BK=32, 24 steps.
// Each wave owns a 128-col slice; in-block cross-wave reduce -> final logits.
#define AS_BYTES 8192
#define BS_BYTES 32768
__global__ __launch_bounds__(256, 2) void mlp_kernel(const float* __restrict__ A,
                                                     const short* __restrict__ BT,
                                                     const float* __restrict__ b1,
                                                     const float* __restrict__ W2,
                                                     float* __restrict__ logits) {
    __shared__ float4v smem[(AS_BYTES + BS_BYTES) / 16];
    char* Asb = (char*)smem;              // 8 KB fp32 A panel (chunk-swizzled)
    char* Bsb = (char*)smem + AS_BYTES;   // 32 KB bf16 B panel

    const int m0 = blockIdx.x * 64;
    const int tid = threadIdx.x, wave = tid >> 6, lane = tid & 63;
    const int quad = lane >> 4, r = lane & 15;

    // DMA descriptors.  A: 8 instrs of 1 KB (this wave does 2).  slot = ia*64+lane,
    // row = slot>>3, c = slot&7; LDS[(row,c)] <- global chunk (row, c^(row&7)).
    int a_go[2], a_lds[2], b_go[8], b_lds[8];
#pragma unroll
    for (int j = 0; j < 2; j++) {
        int ia = wave * 2 + j;
        int row = ia * 8 + (lane >> 3);
        int c = (lane & 7) ^ (row & 7);
        a_go[j] = row * DIM + c * 4;       // float index
        a_lds[j] = ia * 1024;              // byte (wave-uniform)
    }
    // B: 32 instrs of 1 KB (this wave does 8). slot = ib*64+lane, n = slot>>2, c = slot&3.
#pragma unroll
    for (int j = 0; j < 8; j++) {
        int ib = wave * 8 + j;
        int n = ib * 16 + (lane >> 2);
        int c = lane & 3;
        b_go[j] = n * DIM + c * 8;         // short index
        b_lds[j] = ib * 1024;
    }

    float4v acc[4][8] = {};
    const float* Abase = A + (size_t)m0 * DIM;

    for (int p = 0; p < 24; ++p) {
        const int k0 = p * 32;
#pragma unroll
        for (int j = 0; j < 2; j++) gl2lds16(Abase + a_go[j] + k0, Asb + a_lds[j]);
#pragma unroll
        for (int j = 0; j < 8; j++) gl2lds16(BT + b_go[j] + k0, Bsb + b_lds[j]);
        __syncthreads();   // DMA drained (vmcnt) + all waves arrived

        short8 bfr[8];
#pragma unroll
        for (int nf = 0; nf < 8; nf++)
            bfr[nf] = *(const short8*)(Bsb + (wave * 128 + nf * 16 + r) * 64 + quad * 16);
#pragma unroll
        for (int mf = 0; mf < 4; mf++) {
            int row = mf * 16 + r;
            int e0 = (2 * quad) ^ (row & 7);
            float4v f0 = *(const float4v*)(Asb + row * 128 + e0 * 16);        // k=q*8+0..3
            float4v f1 = *(const float4v*)(Asb + row * 128 + (e0 ^ 1) * 16);  // k=q*8+4..7
            FragU af;
            af.u[0] = pack_bf2(f0[0], f0[1]);
            af.u[1] = pack_bf2(f0[2], f0[3]);
            af.u[2] = pack_bf2(f1[0], f1[1]);
            af.u[3] = pack_bf2(f1[2], f1[3]);
#pragma unroll
            for (int nf = 0; nf < 8; nf++)
                acc[mf][nf] = __builtin_amdgcn_mfma_f32_16x16x32_bf16(
                    af.s, bfr[nf], acc[mf][nf], 0, 0, 0);
        }
        __syncthreads();   // frag reads done before next DMA overwrite
    }

    // epilogue: h = relu(acc + b1); per-row partial over this wave's 128 cols
    float b1v[8], w2v[8];
#pragma unroll
    for (int nf = 0; nf < 8; nf++) {
        int gc = wave * 128 + nf * 16 + r;
        b1v[nf] = b1[gc];
        w2v[nf] = W2[gc];
    }
    float* red = (float*)Asb;   // reuse A panel: red[wave*64 + row_local]
#pragma unroll
    for (int mf = 0; mf < 4; mf++)
#pragma unroll
        for (int v = 0; v < 4; v++) {
            float pp = 0.f;
#pragma unroll
            for (int nf = 0; nf < 8; nf++) {
                float hh = acc[mf][nf][v] + b1v[nf];
                hh = hh > 0.f ? hh : 0.f;
                pp += hh * w2v[nf];
            }
#pragma unroll
            for (int off = 1; off < 16; off <<= 1) pp += __shfl_xor(pp, off, 64);
            if (r == 0) red[wave * 64 + mf * 16 + quad * 4 + v] = pp;
        }
    __syncthreads();
    if (tid < 64) {
        float s = red[tid] + red[64 + tid] + red[128 + tid] + red[192 + tid];
        logits[m0 + tid] = s;
    }
}

// ---------- boundary: logits -> hard bits, per-batch scan -> segment starts ----------
__global__ __launch_bounds__(1024) void boundary_kernel(const float* __restrict__ logits,
                                                        const float* __restrict__ b2p,
                                                        const float* __restrict__ noise,
                                                        int* __restrict__ starts,   // [BATCH][SEQ+1]
                                                        int* __restrict__ nseg,     // [BATCH]
                                                        int* __restrict__ nbcount) {// [BATCH]
    const int b = blockIdx.x, tid = threadIdx.x;
    const int base = tid * 4;
    const float b2 = b2p[0];
    int h[4], c = 0;
#pragma unroll
    for (int j = 0; j < 4; j++) {
        int l = base + j;
        float u = noise[b * SEQ + l];
        float lg = logits[b * SEQ + l] + b2 + logf(u) - log1pf(-u);
        h[j] = (lg > 0.f) ? 1 : 0;
        c += h[j];
    }
    const int lane = tid & 63, wid = tid >> 6;
    int inc = c;
    for (int off = 1; off < 64; off <<= 1) {
        int t = __shfl_up(inc, off, 64);
        if (lane >= off) inc += t;
    }
    __shared__ int wtot[16], woff[16], extra[2];
    if (lane == 63) wtot[wid] = inc;
    if (tid == 1023) extra[0] = h[3];
    __syncthreads();
    if (tid == 0) {
        int s = 0;
        for (int i = 0; i < 16; i++) { woff[i] = s; s += wtot[i]; }
        extra[1] = s;
    }
    __syncthreads();
    int run = (inc - c) + woff[wid];       // exclusive prefix of hard bits
#pragma unroll
    for (int j = 0; j < 4; j++) {
        int l = base + j;
        if (h[j]) {
            run++;
            if (l < SEQ - 1) starts[b * (SEQ + 1) + run] = l + 1;
        }
    }
    if (tid == 0) {
        int total = extra[1];
        int ns = total + (extra[0] ? 0 : 1);
        starts[b * (SEQ + 1)] = 0;
        starts[b * (SEQ + 1) + ns] = SEQ;
        nseg[b] = ns;
        nbcount[b] = total;
    }
}

// ---------- pool: 4 waves/block, one wave per slot; 2-way row unroll; NT stores ----------
__global__ __launch_bounds__(256) void pool_kernel(const float* __restrict__ hidden,
                                                   const int* __restrict__ starts,
                                                   const int* __restrict__ nseg,
                                                   float* __restrict__ out) {
    const int wid = threadIdx.x >> 6, lane = threadIdx.x & 63;
    const int s = blockIdx.x * 4 + wid, b = blockIdx.y;
    float* orow = out + (size_t)(b * SEQ + s) * DIM;
    float4v a0 = {0.f, 0.f, 0.f, 0.f}, a1 = a0, a2 = a0;
    const int ns = nseg[b];
    if (s < ns) {
        const int st = starts[b * (SEQ + 1) + s];
        const int en = starts[b * (SEQ + 1) + s + 1];
        float4v c0 = a0, c1 = a0, c2 = a0;
        const float* hbase = hidden + (size_t)(b * SEQ) * DIM;
        int row = st;
        for (; row + 2 <= en; row += 2) {
            const float* h0 = hbase + (size_t)row * DIM;
            const float* h1 = h0 + DIM;
            a0 += *(const float4v*)(h0 + lane * 4);
            a1 += *(const float4v*)(h0 + (lane + 64) * 4);
            a2 += *(const float4v*)(h0 + (lane + 128) * 4);
            c0 += *(const float4v*)(h1 + lane * 4);
            c1 += *(const float4v*)(h1 + (lane + 64) * 4);
            c2 += *(const float4v*)(h1 + (lane + 128) * 4);
        }
        if (row < en) {
            const float* h0 = hbase + (size_t)row * DIM;
            a0 += *(const float4v*)(h0 + lane * 4);
            a1 += *(const float4v*)(h0 + (lane + 64) * 4);
            a2 += *(const float4v*)(h0 + (lane + 128) * 4);
        }
        a0 += c0; a1 += c1; a2 += c2;
        const float invc = 1.f / (float)(en - st);
        a0 *= invc; a1 *= invc; a2 *= invc;
    }
    __builtin_nontemporal_store(a0, (float4v*)(orow + lane * 4));
    __builtin_nontemporal_store(a1, (float4v*)(orow + (lane + 64) * 4));
    __builtin_nontemporal_store(a2, (float4v*)(orow + (lane + 128) * 4));
}

// ---------- finalize: loss / num_boundaries / total_positions ----------
__global__ void finalize_kernel(const int* __restrict__ nbcount, float* __restrict__ tail) {
    int nb = 0;
    for (int i = 0; i < BATCH; i++) nb += nbcount[i];
    float ratio = (float)nb / (float)M_TOK;
    float d = fabsf(ratio - 0.25f) - 0.05f;    // PRIOR + 0.05 = 0.25, margin 0.05
    tail[0] = d > 0.f ? d : 0.f;
    tail[1] = (float)nb;
    tail[2] = (float)M_TOK;
}

// ---------- launch ----------
extern "C" void kernel_launch(void* const* d_in, const int* in_sizes, int n_in,
                              void* d_out, int out_size, void* d_ws, size_t ws_size,
                              hipStream_t stream) {
    const float* hidden = (const float*)d_in[0];
    const float* W1     = (const float*)d_in[1];
    const float* b1     = (const float*)d_in[2];
    const float* W2     = (const float*)d_in[3];
    const float* b2     = (const float*)d_in[4];
    const float* noise  = (const float*)d_in[5];

    char* ws = (char*)d_ws;
    short* W1T    = (short*)(ws);                    // 786432 B
    float* logits = (float*)(ws + 786432);           // 131072 B
    int*   starts = (int*)(ws + 917504);             // 131104 B
    int*   nseg   = (int*)(ws + 917504 + 131104);    // 32 B
    int*   nbcount = nseg + 8;                       // 32 B
    float* out    = (float*)d_out;

    prep_kernel<<<96, 256, 0, stream>>>(W1, W1T);
    mlp_kernel<<<512, 256, 0, stream>>>(hidden, W1T, b1, W2, logits);
    boundary_kernel<<<BATCH, 1024, 0, stream>>>(logits, b2, noise, starts, nseg, nbcount);
    pool_kernel<<<dim3(SEQ / 4, BATCH), 256, 0, stream>>>(hidden, starts, nseg, out);
    finalize_kernel<<<1, 1, 0, stream>>>(nbcount, out + (size_t)M_TOK * DIM);
}